// Round 1
// baseline (485.647 us; speedup 1.0000x reference)
//
#include <hip/hip_runtime.h>

// GNN: 2x GCNConv(relu) + mean-pool + MLP head. All f32.
// Sizes fixed by problem: N=50000, F_IN=256, H=64, NG=64, NC=4, E=800000.

#define TPB 256

// ---------------- CSR build ----------------

__global__ __launch_bounds__(TPB) void k_deg(const int* __restrict__ dstv, int E,
                                             int* __restrict__ cnt) {
    int i = blockIdx.x * TPB + threadIdx.x;
    if (i < E) atomicAdd(&cnt[dstv[i]], 1);
}

// single block, 1024 threads: exclusive scan of cnt -> csr_off, plus dinv = rsqrt(cnt+1)
__global__ __launch_bounds__(1024) void k_scan(const int* __restrict__ cnt, int n,
                                               int* __restrict__ csr_off,
                                               float* __restrict__ dinv) {
    __shared__ int buf[1024];
    int t = threadIdx.x;
    int CH = (n + 1023) / 1024;
    int lo = t * CH;
    int hi = lo + CH; if (hi > n) hi = n;
    int s = 0;
    for (int i = lo; i < hi; i++) s += cnt[i];
    buf[t] = s;
    __syncthreads();
    for (int off = 1; off < 1024; off <<= 1) {
        int v = (t >= off) ? buf[t - off] : 0;
        __syncthreads();
        buf[t] += v;
        __syncthreads();
    }
    int run = buf[t] - s;  // exclusive
    for (int i = lo; i < hi; i++) {
        csr_off[i] = run;
        int c = cnt[i];
        run += c;
        dinv[i] = rsqrtf((float)(c + 1));  // +1 self loop; always > 0
    }
    if (t == 1023) csr_off[n] = buf[1023];
}

__global__ __launch_bounds__(TPB) void k_fill(const int* __restrict__ srcv,
                                              const int* __restrict__ dstv, int E,
                                              const int* __restrict__ csr_off,
                                              int* __restrict__ cursor,
                                              int* __restrict__ csr_src) {
    int i = blockIdx.x * TPB + threadIdx.x;
    if (i < E) {
        int d = dstv[i];
        int p = csr_off[d] + atomicAdd(&cursor[d], 1);
        csr_src[p] = srcv[i];
    }
}

// ---------------- GEMM: C[r][j] = dinv[r] * sum_k A[r][k] * W[k][j], j in [0,64) ----------------
// block tile: 64 rows x 64 cols; K-chunks of 64; per-lane 4x4 register tile.

template <int K>
__global__ __launch_bounds__(TPB) void k_gemm_scaled(const float* __restrict__ A,
                                                     const float* __restrict__ W,
                                                     const float* __restrict__ dinv,
                                                     float* __restrict__ C, int n) {
    __shared__ __align__(16) float Wc[64 * 64];    // W chunk [kk][j]
    __shared__ __align__(16) float xr[64 * 68];    // x chunk [row][kk], padded stride 68
    const int t = threadIdx.x;
    const int wave = t >> 6, lane = t & 63;
    const int li = lane >> 4, lj = lane & 15;
    const int rl0 = wave * 16 + li * 4;            // local row base (4 rows per lane)
    const int rbase = blockIdx.x * 64;

    float acc[4][4] = {{0.f,0.f,0.f,0.f},{0.f,0.f,0.f,0.f},{0.f,0.f,0.f,0.f},{0.f,0.f,0.f,0.f}};

    for (int kc = 0; kc < K; kc += 64) {
        // stage W chunk (4096 floats, contiguous, coalesced)
        {
            const float4* wsv = (const float4*)(W + (size_t)kc * 64);
            float4* wd = (float4*)Wc;
#pragma unroll
            for (int q = 0; q < 4; q++) wd[t + q * 256] = wsv[t + q * 256];
        }
        // stage x chunk: thread t -> row rl = t>>2, k-quarter kq = (t&3)*16
        {
            int rl = t >> 2;
            int kq = (t & 3) * 16;
            int r = rbase + rl;
#pragma unroll
            for (int m = 0; m < 16; m += 4) {
                float4 xv;
                if (r < n) xv = *(const float4*)&A[(size_t)r * K + kc + kq + m];
                else       xv = make_float4(0.f, 0.f, 0.f, 0.f);
                *(float4*)&xr[rl * 68 + kq + m] = xv;
            }
        }
        __syncthreads();
#pragma unroll 8
        for (int kk = 0; kk < 64; kk++) {
            float4 wv = *(const float4*)&Wc[kk * 64 + lj * 4];
            float x0 = xr[(rl0 + 0) * 68 + kk];
            float x1 = xr[(rl0 + 1) * 68 + kk];
            float x2 = xr[(rl0 + 2) * 68 + kk];
            float x3 = xr[(rl0 + 3) * 68 + kk];
            acc[0][0] += x0 * wv.x; acc[0][1] += x0 * wv.y; acc[0][2] += x0 * wv.z; acc[0][3] += x0 * wv.w;
            acc[1][0] += x1 * wv.x; acc[1][1] += x1 * wv.y; acc[1][2] += x1 * wv.z; acc[1][3] += x1 * wv.w;
            acc[2][0] += x2 * wv.x; acc[2][1] += x2 * wv.y; acc[2][2] += x2 * wv.z; acc[2][3] += x2 * wv.w;
            acc[3][0] += x3 * wv.x; acc[3][1] += x3 * wv.y; acc[3][2] += x3 * wv.z; acc[3][3] += x3 * wv.w;
        }
        __syncthreads();
    }

#pragma unroll
    for (int ri = 0; ri < 4; ri++) {
        int r = rbase + rl0 + ri;
        if (r < n) {
            float d = dinv[r];
            float4 o = make_float4(acc[ri][0] * d, acc[ri][1] * d, acc[ri][2] * d, acc[ri][3] * d);
            *(float4*)&C[(size_t)r * 64 + lj * 4] = o;
        }
    }
}

// ---------------- Aggregation: out[i] = relu(dinv[i]*(sum_{src->i} hs[src] + hs[i]) + b) ----------------
// one wave per node; 64 lanes = 64 features.

__global__ __launch_bounds__(TPB) void k_agg(const float* __restrict__ hs,
                                             const int* __restrict__ csr_off,
                                             const int* __restrict__ csr_src,
                                             const float* __restrict__ dinv,
                                             const float* __restrict__ bias,
                                             float* __restrict__ out, int n) {
    int node = blockIdx.x * 4 + (threadIdx.x >> 6);
    int lane = threadIdx.x & 63;
    if (node >= n) return;
    int p0 = csr_off[node];
    int p1 = csr_off[node + 1];
    float acc = hs[(size_t)node * 64 + lane];  // self loop
    int p = p0;
    for (; p + 4 <= p1; p += 4) {
        int s0 = csr_src[p + 0];
        int s1 = csr_src[p + 1];
        int s2 = csr_src[p + 2];
        int s3 = csr_src[p + 3];
        float a0 = hs[(size_t)s0 * 64 + lane];
        float a1 = hs[(size_t)s1 * 64 + lane];
        float a2 = hs[(size_t)s2 * 64 + lane];
        float a3 = hs[(size_t)s3 * 64 + lane];
        acc += (a0 + a1) + (a2 + a3);
    }
    for (; p < p1; p++) acc += hs[(size_t)csr_src[p] * 64 + lane];
    float v = dinv[node] * acc + bias[lane];
    out[(size_t)node * 64 + lane] = fmaxf(v, 0.f);
}

// ---------------- Pool: batch is sorted; per-wave run-length accumulate, atomic flush ----------------

__global__ __launch_bounds__(TPB) void k_pool(const float* __restrict__ h,
                                              const int* __restrict__ batch, int n,
                                              float* __restrict__ gsum,
                                              int* __restrict__ gcnt) {
    const int CH = 128;
    int wid = blockIdx.x * 4 + (threadIdx.x >> 6);
    int lane = threadIdx.x & 63;
    int i0 = wid * CH;
    if (i0 >= n) return;
    int i1 = i0 + CH; if (i1 > n) i1 = n;
    int cur = batch[i0];
    float acc = 0.f;
    int cnt = 0;
    for (int i = i0; i < i1; i++) {
        int g = batch[i];               // wave-uniform
        if (g != cur) {
            atomicAdd(&gsum[cur * 64 + lane], acc);
            if (lane == 0) atomicAdd(&gcnt[cur], cnt);
            acc = 0.f; cnt = 0; cur = g;
        }
        acc += h[(size_t)i * 64 + lane];
        cnt++;
    }
    atomicAdd(&gsum[cur * 64 + lane], acc);
    if (lane == 0) atomicAdd(&gcnt[cur], cnt);
}

// ---------------- Head: pooled = gsum/cnt; z = relu(pooled@fc1 + b); out = z@fc2 + b ----------------

__global__ __launch_bounds__(TPB) void k_mlp(const float* __restrict__ gsum,
                                             const int* __restrict__ gcnt,
                                             const float* __restrict__ fc1w,
                                             const float* __restrict__ fc1b,
                                             const float* __restrict__ fc2w,
                                             const float* __restrict__ fc2b,
                                             float* __restrict__ out) {
    __shared__ float pooled[64 * 64];
    __shared__ float z[64 * 128];
    int t = threadIdx.x;
    for (int idx = t; idx < 64 * 64; idx += TPB) {
        int g = idx >> 6;
        int c = gcnt[g]; if (c < 1) c = 1;
        pooled[idx] = gsum[idx] / (float)c;
    }
    __syncthreads();
    for (int idx = t; idx < 64 * 128; idx += TPB) {
        int g = idx >> 7, o = idx & 127;
        float a = fc1b[o];
#pragma unroll 8
        for (int j = 0; j < 64; j++) a += pooled[g * 64 + j] * fc1w[j * 128 + o];
        z[idx] = fmaxf(a, 0.f);
    }
    __syncthreads();
    {
        int g = t >> 2, c = t & 3;
        float a = fc2b[c];
#pragma unroll 8
        for (int o = 0; o < 128; o++) a += z[g * 128 + o] * fc2w[o * 4 + c];
        out[t] = a;
    }
}

// ---------------- launch ----------------

extern "C" void kernel_launch(void* const* d_in, const int* in_sizes, int n_in,
                              void* d_out, int out_size, void* d_ws, size_t ws_size,
                              hipStream_t stream) {
    const float* x    = (const float*)d_in[0];
    const int*   ei   = (const int*)d_in[1];   // [2][E] int32 per harness convention
    const int*   batch= (const int*)d_in[2];
    const float* W1   = (const float*)d_in[3];
    const float* b1   = (const float*)d_in[4];
    const float* W2   = (const float*)d_in[5];
    const float* b2   = (const float*)d_in[6];
    const float* fc1w = (const float*)d_in[7];
    const float* fc1b = (const float*)d_in[8];
    const float* fc2w = (const float*)d_in[9];
    const float* fc2b = (const float*)d_in[10];

    const int n = in_sizes[2];        // 50000
    const int E = in_sizes[1] / 2;    // 800000
    const int* srcv = ei;
    const int* dstv = ei + E;

    // workspace carve (all 4-byte types; keep zeroed region contiguous at front)
    char* w = (char*)d_ws;
    int*   cnt    = (int*)w;            w += (size_t)n * 4;
    int*   cursor = (int*)w;            w += (size_t)n * 4;
    int*   gcnt   = (int*)w;            w += 64 * 4;
    float* gsum   = (float*)w;          w += 64 * 64 * 4;
    size_t zbytes = (size_t)w - (size_t)d_ws;
    int*   csr_off= (int*)w;            w += (size_t)(n + 1) * 4;
    float* dinv   = (float*)w;          w += (size_t)n * 4;
    int*   csr_src= (int*)w;            w += (size_t)E * 4;
    // align to 256B for float4 traffic
    w = (char*)(((size_t)w + 255) & ~(size_t)255);
    float* hs = (float*)w;              w += (size_t)n * 64 * 4;
    float* hb = (float*)w;              w += (size_t)n * 64 * 4;

    hipMemsetAsync(d_ws, 0, zbytes, stream);

    int gE = (E + TPB - 1) / TPB;
    k_deg<<<gE, TPB, 0, stream>>>(dstv, E, cnt);
    k_scan<<<1, 1024, 0, stream>>>(cnt, n, csr_off, dinv);
    k_fill<<<gE, TPB, 0, stream>>>(srcv, dstv, E, csr_off, cursor, csr_src);

    int gRows = (n + 63) / 64;
    int gNode = (n + 3) / 4;
    k_gemm_scaled<256><<<gRows, TPB, 0, stream>>>(x, W1, dinv, hs, n);
    k_agg<<<gNode, TPB, 0, stream>>>(hs, csr_off, csr_src, dinv, b1, hb, n);
    k_gemm_scaled<64><<<gRows, TPB, 0, stream>>>(hb, W2, dinv, hs, n);
    k_agg<<<gNode, TPB, 0, stream>>>(hs, csr_off, csr_src, dinv, b2, hb, n);

    int nwaves = (n + 127) / 128;
    k_pool<<<(nwaves + 3) / 4, TPB, 0, stream>>>(hb, batch, n, gsum, gcnt);
    k_mlp<<<1, TPB, 0, stream>>>(gsum, gcnt, fc1w, fc1b, fc2w, fc2b, (float*)d_out);
}

// Round 2
// 383.896 us; speedup vs baseline: 1.2650x; 1.2650x over previous
//
#include <hip/hip_runtime.h>

// GNN: 2x GCNConv(relu) + mean-pool + MLP head. All f32.
// Sizes fixed by problem: N=50000, F_IN=256, H=64, NG=64, NC=4, E=800000.

#define TPB 256
#define SCAN_CHUNK 1024   // elements per block in hierarchical scan

// ---------------- CSR build ----------------

__global__ __launch_bounds__(TPB) void k_deg(const int* __restrict__ dstv, int E,
                                             int* __restrict__ cnt) {
    int i = blockIdx.x * TPB + threadIdx.x;
    if (i < E) atomicAdd(&cnt[dstv[i]], 1);
}

// ---- hierarchical exclusive scan of cnt -> csr_off (+ dinv = rsqrt(cnt+1)) ----
// phase 1: per-block sums (block covers SCAN_CHUNK elements, int4 loads)
__global__ __launch_bounds__(TPB) void k_scan1(const int* __restrict__ cnt, int n,
                                               int* __restrict__ bsum) {
    int t = threadIdx.x;
    int base = blockIdx.x * SCAN_CHUNK + t * 4;
    int s = 0;
    if (base + 4 <= n) {
        int4 v = *(const int4*)(cnt + base);
        s = v.x + v.y + v.z + v.w;
    } else {
        for (int i = base; i < n; i++) s += cnt[i];
    }
    __shared__ int r[TPB];
    r[t] = s;
    __syncthreads();
    for (int off = 128; off > 0; off >>= 1) {
        if (t < off) r[t] += r[t + off];
        __syncthreads();
    }
    if (t == 0) bsum[blockIdx.x] = r[0];
}

// phase 2: single small block scans the (<=256) block sums; also writes csr_off[n]
__global__ __launch_bounds__(TPB) void k_scan2(const int* __restrict__ bsum, int nb,
                                               int* __restrict__ boff,
                                               int* __restrict__ csr_off, int n) {
    __shared__ int r[TPB];
    int t = threadIdx.x;
    int v = (t < nb) ? bsum[t] : 0;
    r[t] = v;
    __syncthreads();
    for (int off = 1; off < TPB; off <<= 1) {
        int u = (t >= off) ? r[t - off] : 0;
        __syncthreads();
        r[t] += u;
        __syncthreads();
    }
    if (t < nb) boff[t] = r[t] - v;      // exclusive block offset
    if (t == TPB - 1) csr_off[n] = r[TPB - 1];
}

// phase 3: per-block local scan + apply; writes csr_off[i] and dinv[i]
__global__ __launch_bounds__(TPB) void k_scan3(const int* __restrict__ cnt, int n,
                                               const int* __restrict__ boff,
                                               int* __restrict__ csr_off,
                                               float* __restrict__ dinv) {
    int t = threadIdx.x;
    int base = blockIdx.x * SCAN_CHUNK + t * 4;
    int4 v = make_int4(0, 0, 0, 0);
    bool full = (base + 4 <= n);
    if (full) {
        v = *(const int4*)(cnt + base);
    } else {
        int tmp[4] = {0, 0, 0, 0};
        for (int i = 0; i < 4; i++) if (base + i < n) tmp[i] = cnt[base + i];
        v = make_int4(tmp[0], tmp[1], tmp[2], tmp[3]);
    }
    int s = v.x + v.y + v.z + v.w;
    __shared__ int r[TPB];
    r[t] = s;
    __syncthreads();
    for (int off = 1; off < TPB; off <<= 1) {
        int u = (t >= off) ? r[t - off] : 0;
        __syncthreads();
        r[t] += u;
        __syncthreads();
    }
    int run = boff[blockIdx.x] + r[t] - s;  // exclusive over elements before this thread
    if (full) {
        int4 o;
        o.x = run;
        o.y = run + v.x;
        o.z = o.y + v.y;
        o.w = o.z + v.z;
        *(int4*)(csr_off + base) = o;
        float4 dv;
        dv.x = rsqrtf((float)(v.x + 1));
        dv.y = rsqrtf((float)(v.y + 1));
        dv.z = rsqrtf((float)(v.z + 1));
        dv.w = rsqrtf((float)(v.w + 1));
        *(float4*)(dinv + base) = dv;
    } else {
        int e[4] = {v.x, v.y, v.z, v.w};
        for (int i = 0; i < 4; i++) {
            int idx = base + i;
            if (idx < n) {
                csr_off[idx] = run;
                dinv[idx] = rsqrtf((float)(e[i] + 1));
                run += e[i];
            }
        }
    }
}

__global__ __launch_bounds__(TPB) void k_fill(const int* __restrict__ srcv,
                                              const int* __restrict__ dstv, int E,
                                              const int* __restrict__ csr_off,
                                              int* __restrict__ cursor,
                                              int* __restrict__ csr_src) {
    int i = blockIdx.x * TPB + threadIdx.x;
    if (i < E) {
        int d = dstv[i];
        int p = csr_off[d] + atomicAdd(&cursor[d], 1);
        csr_src[p] = srcv[i];
    }
}

// ---------------- GEMM: C[r][j] = dinv[r] * sum_k A[r][k] * W[k][j], j in [0,64) ----------------
// block tile: 64 rows x 64 cols; K-chunks of 64; per-lane 4x4 register tile.

template <int K>
__global__ __launch_bounds__(TPB) void k_gemm_scaled(const float* __restrict__ A,
                                                     const float* __restrict__ W,
                                                     const float* __restrict__ dinv,
                                                     float* __restrict__ C, int n) {
    __shared__ __align__(16) float Wc[64 * 64];    // W chunk [kk][j]
    __shared__ __align__(16) float xr[64 * 68];    // x chunk [row][kk], padded stride 68
    const int t = threadIdx.x;
    const int wave = t >> 6, lane = t & 63;
    const int li = lane >> 4, lj = lane & 15;
    const int rl0 = wave * 16 + li * 4;            // local row base (4 rows per lane)
    const int rbase = blockIdx.x * 64;

    float acc[4][4] = {{0.f,0.f,0.f,0.f},{0.f,0.f,0.f,0.f},{0.f,0.f,0.f,0.f},{0.f,0.f,0.f,0.f}};

    for (int kc = 0; kc < K; kc += 64) {
        // stage W chunk (4096 floats, contiguous, coalesced)
        {
            const float4* wsv = (const float4*)(W + (size_t)kc * 64);
            float4* wd = (float4*)Wc;
#pragma unroll
            for (int q = 0; q < 4; q++) wd[t + q * 256] = wsv[t + q * 256];
        }
        // stage x chunk: thread t -> row rl = t>>2, k-quarter kq = (t&3)*16
        {
            int rl = t >> 2;
            int kq = (t & 3) * 16;
            int r = rbase + rl;
#pragma unroll
            for (int m = 0; m < 16; m += 4) {
                float4 xv;
                if (r < n) xv = *(const float4*)&A[(size_t)r * K + kc + kq + m];
                else       xv = make_float4(0.f, 0.f, 0.f, 0.f);
                *(float4*)&xr[rl * 68 + kq + m] = xv;
            }
        }
        __syncthreads();
#pragma unroll 8
        for (int kk = 0; kk < 64; kk++) {
            float4 wv = *(const float4*)&Wc[kk * 64 + lj * 4];
            float x0 = xr[(rl0 + 0) * 68 + kk];
            float x1 = xr[(rl0 + 1) * 68 + kk];
            float x2 = xr[(rl0 + 2) * 68 + kk];
            float x3 = xr[(rl0 + 3) * 68 + kk];
            acc[0][0] += x0 * wv.x; acc[0][1] += x0 * wv.y; acc[0][2] += x0 * wv.z; acc[0][3] += x0 * wv.w;
            acc[1][0] += x1 * wv.x; acc[1][1] += x1 * wv.y; acc[1][2] += x1 * wv.z; acc[1][3] += x1 * wv.w;
            acc[2][0] += x2 * wv.x; acc[2][1] += x2 * wv.y; acc[2][2] += x2 * wv.z; acc[2][3] += x2 * wv.w;
            acc[3][0] += x3 * wv.x; acc[3][1] += x3 * wv.y; acc[3][2] += x3 * wv.z; acc[3][3] += x3 * wv.w;
        }
        __syncthreads();
    }

#pragma unroll
    for (int ri = 0; ri < 4; ri++) {
        int r = rbase + rl0 + ri;
        if (r < n) {
            float d = dinv[r];
            float4 o = make_float4(acc[ri][0] * d, acc[ri][1] * d, acc[ri][2] * d, acc[ri][3] * d);
            *(float4*)&C[(size_t)r * 64 + lj * 4] = o;
        }
    }
}

// ---------------- Aggregation: out[i] = relu(dinv[i]*(sum_{src->i} hs[src] + hs[i]) + b) ----------------
// one wave per node; 64 lanes = 64 features.

__global__ __launch_bounds__(TPB) void k_agg(const float* __restrict__ hs,
                                             const int* __restrict__ csr_off,
                                             const int* __restrict__ csr_src,
                                             const float* __restrict__ dinv,
                                             const float* __restrict__ bias,
                                             float* __restrict__ out, int n) {
    int node = blockIdx.x * 4 + (threadIdx.x >> 6);
    int lane = threadIdx.x & 63;
    if (node >= n) return;
    int p0 = csr_off[node];
    int p1 = csr_off[node + 1];
    float acc = hs[(size_t)node * 64 + lane];  // self loop
    int p = p0;
    for (; p + 4 <= p1; p += 4) {
        int s0 = csr_src[p + 0];
        int s1 = csr_src[p + 1];
        int s2 = csr_src[p + 2];
        int s3 = csr_src[p + 3];
        float a0 = hs[(size_t)s0 * 64 + lane];
        float a1 = hs[(size_t)s1 * 64 + lane];
        float a2 = hs[(size_t)s2 * 64 + lane];
        float a3 = hs[(size_t)s3 * 64 + lane];
        acc += (a0 + a1) + (a2 + a3);
    }
    for (; p < p1; p++) acc += hs[(size_t)csr_src[p] * 64 + lane];
    float v = dinv[node] * acc + bias[lane];
    out[(size_t)node * 64 + lane] = fmaxf(v, 0.f);
}

// ---------------- Pool: batch is sorted; per-wave run-length accumulate, atomic flush ----------------

__global__ __launch_bounds__(TPB) void k_pool(const float* __restrict__ h,
                                              const int* __restrict__ batch, int n,
                                              float* __restrict__ gsum,
                                              int* __restrict__ gcnt) {
    const int CH = 128;
    int wid = blockIdx.x * 4 + (threadIdx.x >> 6);
    int lane = threadIdx.x & 63;
    int i0 = wid * CH;
    if (i0 >= n) return;
    int i1 = i0 + CH; if (i1 > n) i1 = n;
    int cur = batch[i0];
    float acc = 0.f;
    int cnt = 0;
    for (int i = i0; i < i1; i++) {
        int g = batch[i];               // wave-uniform
        if (g != cur) {
            atomicAdd(&gsum[cur * 64 + lane], acc);
            if (lane == 0) atomicAdd(&gcnt[cur], cnt);
            acc = 0.f; cnt = 0; cur = g;
        }
        acc += h[(size_t)i * 64 + lane];
        cnt++;
    }
    atomicAdd(&gsum[cur * 64 + lane], acc);
    if (lane == 0) atomicAdd(&gcnt[cur], cnt);
}

// ---------------- Head: pooled = gsum/cnt; z = relu(pooled@fc1 + b); out = z@fc2 + b ----------------

__global__ __launch_bounds__(TPB) void k_mlp(const float* __restrict__ gsum,
                                             const int* __restrict__ gcnt,
                                             const float* __restrict__ fc1w,
                                             const float* __restrict__ fc1b,
                                             const float* __restrict__ fc2w,
                                             const float* __restrict__ fc2b,
                                             float* __restrict__ out) {
    __shared__ float pooled[64 * 64];
    __shared__ float z[64 * 128];
    int t = threadIdx.x;
    for (int idx = t; idx < 64 * 64; idx += TPB) {
        int g = idx >> 6;
        int c = gcnt[g]; if (c < 1) c = 1;
        pooled[idx] = gsum[idx] / (float)c;
    }
    __syncthreads();
    for (int idx = t; idx < 64 * 128; idx += TPB) {
        int g = idx >> 7, o = idx & 127;
        float a = fc1b[o];
#pragma unroll 8
        for (int j = 0; j < 64; j++) a += pooled[g * 64 + j] * fc1w[j * 128 + o];
        z[idx] = fmaxf(a, 0.f);
    }
    __syncthreads();
    {
        int g = t >> 2, c = t & 3;
        float a = fc2b[c];
#pragma unroll 8
        for (int o = 0; o < 128; o++) a += z[g * 128 + o] * fc2w[o * 4 + c];
        out[t] = a;
    }
}

// ---------------- launch ----------------

extern "C" void kernel_launch(void* const* d_in, const int* in_sizes, int n_in,
                              void* d_out, int out_size, void* d_ws, size_t ws_size,
                              hipStream_t stream) {
    const float* x    = (const float*)d_in[0];
    const int*   ei   = (const int*)d_in[1];   // [2][E] int32 per harness convention
    const int*   batch= (const int*)d_in[2];
    const float* W1   = (const float*)d_in[3];
    const float* b1   = (const float*)d_in[4];
    const float* W2   = (const float*)d_in[5];
    const float* b2   = (const float*)d_in[6];
    const float* fc1w = (const float*)d_in[7];
    const float* fc1b = (const float*)d_in[8];
    const float* fc2w = (const float*)d_in[9];
    const float* fc2b = (const float*)d_in[10];

    const int n = in_sizes[2];        // 50000
    const int E = in_sizes[1] / 2;    // 800000
    const int* srcv = ei;
    const int* dstv = ei + E;

    // workspace carve (all 4-byte types; keep zeroed region contiguous at front)
    char* w = (char*)d_ws;
    int*   cnt    = (int*)w;            w += (size_t)n * 4;
    int*   cursor = (int*)w;            w += (size_t)n * 4;
    int*   gcnt   = (int*)w;            w += 64 * 4;
    float* gsum   = (float*)w;          w += 64 * 64 * 4;
    size_t zbytes = (size_t)w - (size_t)d_ws;
    int*   csr_off= (int*)w;            w += (size_t)(n + 1) * 4;
    float* dinv   = (float*)w;          w += (size_t)n * 4;
    int*   csr_src= (int*)w;            w += (size_t)E * 4;
    int*   bsum   = (int*)w;            w += 256 * 4;
    int*   boff   = (int*)w;            w += 256 * 4;
    // align to 256B for float4 traffic
    w = (char*)(((size_t)w + 255) & ~(size_t)255);
    float* hs = (float*)w;              w += (size_t)n * 64 * 4;
    float* hb = (float*)w;              w += (size_t)n * 64 * 4;

    hipMemsetAsync(d_ws, 0, zbytes, stream);

    int gE = (E + TPB - 1) / TPB;
    k_deg<<<gE, TPB, 0, stream>>>(dstv, E, cnt);

    int nb = (n + SCAN_CHUNK - 1) / SCAN_CHUNK;   // 49 for n=50000 (must be <= 256)
    k_scan1<<<nb, TPB, 0, stream>>>(cnt, n, bsum);
    k_scan2<<<1, TPB, 0, stream>>>(bsum, nb, boff, csr_off, n);
    k_scan3<<<nb, TPB, 0, stream>>>(cnt, n, boff, csr_off, dinv);

    k_fill<<<gE, TPB, 0, stream>>>(srcv, dstv, E, csr_off, cursor, csr_src);

    int gRows = (n + 63) / 64;
    int gNode = (n + 3) / 4;
    k_gemm_scaled<256><<<gRows, TPB, 0, stream>>>(x, W1, dinv, hs, n);
    k_agg<<<gNode, TPB, 0, stream>>>(hs, csr_off, csr_src, dinv, b1, hb, n);
    k_gemm_scaled<64><<<gRows, TPB, 0, stream>>>(hb, W2, dinv, hs, n);
    k_agg<<<gNode, TPB, 0, stream>>>(hs, csr_off, csr_src, dinv, b2, hb, n);

    int nwaves = (n + 127) / 128;
    k_pool<<<(nwaves + 3) / 4, TPB, 0, stream>>>(hb, batch, n, gsum, gcnt);
    k_mlp<<<1, TPB, 0, stream>>>(gsum, gcnt, fc1w, fc1b, fc2w, fc2b, (float*)d_out);
}

// Round 3
// 364.512 us; speedup vs baseline: 1.3323x; 1.0532x over previous
//
#include <hip/hip_runtime.h>

// GNN: 2x GCNConv(relu) + mean-pool + MLP head. All f32.
// Sizes fixed by problem: N=50000, F_IN=256, H=64, NG=64, NC=4, E=800000.

#define TPB 256
#define SCAN_CHUNK 1024   // elements per block in hierarchical scan

// ---------------- CSR build ----------------

__global__ __launch_bounds__(TPB) void k_deg(const int* __restrict__ dstv, int E,
                                             int* __restrict__ cnt) {
    int i = blockIdx.x * TPB + threadIdx.x;
    if (i < E) atomicAdd(&cnt[dstv[i]], 1);
}

// ---- hierarchical exclusive scan of cnt -> csr_off (+ dinv = rsqrt(cnt+1)) ----
__global__ __launch_bounds__(TPB) void k_scan1(const int* __restrict__ cnt, int n,
                                               int* __restrict__ bsum) {
    int t = threadIdx.x;
    int base = blockIdx.x * SCAN_CHUNK + t * 4;
    int s = 0;
    if (base + 4 <= n) {
        int4 v = *(const int4*)(cnt + base);
        s = v.x + v.y + v.z + v.w;
    } else {
        for (int i = base; i < n; i++) s += cnt[i];
    }
    __shared__ int r[TPB];
    r[t] = s;
    __syncthreads();
    for (int off = 128; off > 0; off >>= 1) {
        if (t < off) r[t] += r[t + off];
        __syncthreads();
    }
    if (t == 0) bsum[blockIdx.x] = r[0];
}

__global__ __launch_bounds__(TPB) void k_scan2(const int* __restrict__ bsum, int nb,
                                               int* __restrict__ boff,
                                               int* __restrict__ csr_off, int n) {
    __shared__ int r[TPB];
    int t = threadIdx.x;
    int v = (t < nb) ? bsum[t] : 0;
    r[t] = v;
    __syncthreads();
    for (int off = 1; off < TPB; off <<= 1) {
        int u = (t >= off) ? r[t - off] : 0;
        __syncthreads();
        r[t] += u;
        __syncthreads();
    }
    if (t < nb) boff[t] = r[t] - v;      // exclusive block offset
    if (t == TPB - 1) csr_off[n] = r[TPB - 1];
}

__global__ __launch_bounds__(TPB) void k_scan3(const int* __restrict__ cnt, int n,
                                               const int* __restrict__ boff,
                                               int* __restrict__ csr_off,
                                               float* __restrict__ dinv) {
    int t = threadIdx.x;
    int base = blockIdx.x * SCAN_CHUNK + t * 4;
    int4 v = make_int4(0, 0, 0, 0);
    bool full = (base + 4 <= n);
    if (full) {
        v = *(const int4*)(cnt + base);
    } else {
        int tmp[4] = {0, 0, 0, 0};
        for (int i = 0; i < 4; i++) if (base + i < n) tmp[i] = cnt[base + i];
        v = make_int4(tmp[0], tmp[1], tmp[2], tmp[3]);
    }
    int s = v.x + v.y + v.z + v.w;
    __shared__ int r[TPB];
    r[t] = s;
    __syncthreads();
    for (int off = 1; off < TPB; off <<= 1) {
        int u = (t >= off) ? r[t - off] : 0;
        __syncthreads();
        r[t] += u;
        __syncthreads();
    }
    int run = boff[blockIdx.x] + r[t] - s;
    if (full) {
        int4 o;
        o.x = run;
        o.y = run + v.x;
        o.z = o.y + v.y;
        o.w = o.z + v.z;
        *(int4*)(csr_off + base) = o;
        float4 dv;
        dv.x = rsqrtf((float)(v.x + 1));
        dv.y = rsqrtf((float)(v.y + 1));
        dv.z = rsqrtf((float)(v.z + 1));
        dv.w = rsqrtf((float)(v.w + 1));
        *(float4*)(dinv + base) = dv;
    } else {
        int e[4] = {v.x, v.y, v.z, v.w};
        for (int i = 0; i < 4; i++) {
            int idx = base + i;
            if (idx < n) {
                csr_off[idx] = run;
                dinv[idx] = rsqrtf((float)(e[i] + 1));
                run += e[i];
            }
        }
    }
}

__global__ __launch_bounds__(TPB) void k_fill(const int* __restrict__ srcv,
                                              const int* __restrict__ dstv, int E,
                                              const int* __restrict__ csr_off,
                                              int* __restrict__ cursor,
                                              int* __restrict__ csr_src) {
    int i = blockIdx.x * TPB + threadIdx.x;
    if (i < E) {
        int d = dstv[i];
        int p = csr_off[d] + atomicAdd(&cursor[d], 1);
        csr_src[p] = srcv[i];
    }
}

// ---------------- GEMM: C[r][j] = dinv[r] * sum_k A[r][k] * W[k][j], j in [0,64) ----------------

template <int K>
__global__ __launch_bounds__(TPB) void k_gemm_scaled(const float* __restrict__ A,
                                                     const float* __restrict__ W,
                                                     const float* __restrict__ dinv,
                                                     float* __restrict__ C, int n) {
    __shared__ __align__(16) float Wc[64 * 64];
    __shared__ __align__(16) float xr[64 * 68];
    const int t = threadIdx.x;
    const int wave = t >> 6, lane = t & 63;
    const int li = lane >> 4, lj = lane & 15;
    const int rl0 = wave * 16 + li * 4;
    const int rbase = blockIdx.x * 64;

    float acc[4][4] = {{0.f,0.f,0.f,0.f},{0.f,0.f,0.f,0.f},{0.f,0.f,0.f,0.f},{0.f,0.f,0.f,0.f}};

    for (int kc = 0; kc < K; kc += 64) {
        {
            const float4* wsv = (const float4*)(W + (size_t)kc * 64);
            float4* wd = (float4*)Wc;
#pragma unroll
            for (int q = 0; q < 4; q++) wd[t + q * 256] = wsv[t + q * 256];
        }
        {
            int rl = t >> 2;
            int kq = (t & 3) * 16;
            int r = rbase + rl;
#pragma unroll
            for (int m = 0; m < 16; m += 4) {
                float4 xv;
                if (r < n) xv = *(const float4*)&A[(size_t)r * K + kc + kq + m];
                else       xv = make_float4(0.f, 0.f, 0.f, 0.f);
                *(float4*)&xr[rl * 68 + kq + m] = xv;
            }
        }
        __syncthreads();
#pragma unroll 8
        for (int kk = 0; kk < 64; kk++) {
            float4 wv = *(const float4*)&Wc[kk * 64 + lj * 4];
            float x0 = xr[(rl0 + 0) * 68 + kk];
            float x1 = xr[(rl0 + 1) * 68 + kk];
            float x2 = xr[(rl0 + 2) * 68 + kk];
            float x3 = xr[(rl0 + 3) * 68 + kk];
            acc[0][0] += x0 * wv.x; acc[0][1] += x0 * wv.y; acc[0][2] += x0 * wv.z; acc[0][3] += x0 * wv.w;
            acc[1][0] += x1 * wv.x; acc[1][1] += x1 * wv.y; acc[1][2] += x1 * wv.z; acc[1][3] += x1 * wv.w;
            acc[2][0] += x2 * wv.x; acc[2][1] += x2 * wv.y; acc[2][2] += x2 * wv.z; acc[2][3] += x2 * wv.w;
            acc[3][0] += x3 * wv.x; acc[3][1] += x3 * wv.y; acc[3][2] += x3 * wv.z; acc[3][3] += x3 * wv.w;
        }
        __syncthreads();
    }

#pragma unroll
    for (int ri = 0; ri < 4; ri++) {
        int r = rbase + rl0 + ri;
        if (r < n) {
            float d = dinv[r];
            float4 o = make_float4(acc[ri][0] * d, acc[ri][1] * d, acc[ri][2] * d, acc[ri][3] * d);
            *(float4*)&C[(size_t)r * 64 + lj * 4] = o;
        }
    }
}

// ---------------- Aggregation ----------------

__global__ __launch_bounds__(TPB) void k_agg(const float* __restrict__ hs,
                                             const int* __restrict__ csr_off,
                                             const int* __restrict__ csr_src,
                                             const float* __restrict__ dinv,
                                             const float* __restrict__ bias,
                                             float* __restrict__ out, int n) {
    int node = blockIdx.x * 4 + (threadIdx.x >> 6);
    int lane = threadIdx.x & 63;
    if (node >= n) return;
    int p0 = csr_off[node];
    int p1 = csr_off[node + 1];
    float acc = hs[(size_t)node * 64 + lane];  // self loop
    int p = p0;
    for (; p + 4 <= p1; p += 4) {
        int s0 = csr_src[p + 0];
        int s1 = csr_src[p + 1];
        int s2 = csr_src[p + 2];
        int s3 = csr_src[p + 3];
        float a0 = hs[(size_t)s0 * 64 + lane];
        float a1 = hs[(size_t)s1 * 64 + lane];
        float a2 = hs[(size_t)s2 * 64 + lane];
        float a3 = hs[(size_t)s3 * 64 + lane];
        acc += (a0 + a1) + (a2 + a3);
    }
    for (; p < p1; p++) acc += hs[(size_t)csr_src[p] * 64 + lane];
    float v = dinv[node] * acc + bias[lane];
    out[(size_t)node * 64 + lane] = fmaxf(v, 0.f);
}

// ---------------- Pool: sorted batch; uniform-chunk fast path ----------------
// CH=16: 3125 waves (~12/CU). At most 63 chunks contain a group boundary.

__global__ __launch_bounds__(TPB) void k_pool(const float* __restrict__ h,
                                              const int* __restrict__ batch, int n,
                                              float* __restrict__ gsum,
                                              int* __restrict__ gcnt) {
    const int CH = 16;
    int wid = blockIdx.x * 4 + (threadIdx.x >> 6);
    int lane = threadIdx.x & 63;
    int i0 = wid * CH;
    if (i0 >= n) return;
    int i1 = i0 + CH; if (i1 > n) i1 = n;
    int g0 = batch[i0];
    int g1 = batch[i1 - 1];
    if (g0 == g1) {
        // branch-free: all loads pipelined
        float acc = 0.f;
#pragma unroll
        for (int i = 0; i < CH; i++) {
            int idx = i0 + i;
            if (idx < i1) acc += h[(size_t)idx * 64 + lane];
        }
        atomicAdd(&gsum[g0 * 64 + lane], acc);
        if (lane == 0) atomicAdd(&gcnt[g0], i1 - i0);
    } else {
        // rare: chunk spans a group boundary
        int cur = g0;
        float acc = 0.f;
        int cnt = 0;
        for (int i = i0; i < i1; i++) {
            int g = batch[i];
            if (g != cur) {
                atomicAdd(&gsum[cur * 64 + lane], acc);
                if (lane == 0) atomicAdd(&gcnt[cur], cnt);
                acc = 0.f; cnt = 0; cur = g;
            }
            acc += h[(size_t)i * 64 + lane];
            cnt++;
        }
        atomicAdd(&gsum[cur * 64 + lane], acc);
        if (lane == 0) atomicAdd(&gcnt[cur], cnt);
    }
}

// ---------------- Head ----------------

__global__ __launch_bounds__(TPB) void k_mlp(const float* __restrict__ gsum,
                                             const int* __restrict__ gcnt,
                                             const float* __restrict__ fc1w,
                                             const float* __restrict__ fc1b,
                                             const float* __restrict__ fc2w,
                                             const float* __restrict__ fc2b,
                                             float* __restrict__ out) {
    __shared__ float pooled[64 * 64];
    __shared__ float z[64 * 128];
    int t = threadIdx.x;
    for (int idx = t; idx < 64 * 64; idx += TPB) {
        int g = idx >> 6;
        int c = gcnt[g]; if (c < 1) c = 1;
        pooled[idx] = gsum[idx] / (float)c;
    }
    __syncthreads();
    for (int idx = t; idx < 64 * 128; idx += TPB) {
        int g = idx >> 7, o = idx & 127;
        float a = fc1b[o];
#pragma unroll 8
        for (int j = 0; j < 64; j++) a += pooled[g * 64 + j] * fc1w[j * 128 + o];
        z[idx] = fmaxf(a, 0.f);
    }
    __syncthreads();
    {
        int g = t >> 2, c = t & 3;
        float a = fc2b[c];
#pragma unroll 8
        for (int o = 0; o < 128; o++) a += z[g * 128 + o] * fc2w[o * 4 + c];
        out[t] = a;
    }
}

// ---------------- launch ----------------

extern "C" void kernel_launch(void* const* d_in, const int* in_sizes, int n_in,
                              void* d_out, int out_size, void* d_ws, size_t ws_size,
                              hipStream_t stream) {
    const float* x    = (const float*)d_in[0];
    const int*   ei   = (const int*)d_in[1];
    const int*   batch= (const int*)d_in[2];
    const float* W1   = (const float*)d_in[3];
    const float* b1   = (const float*)d_in[4];
    const float* W2   = (const float*)d_in[5];
    const float* b2   = (const float*)d_in[6];
    const float* fc1w = (const float*)d_in[7];
    const float* fc1b = (const float*)d_in[8];
    const float* fc2w = (const float*)d_in[9];
    const float* fc2b = (const float*)d_in[10];

    const int n = in_sizes[2];        // 50000
    const int E = in_sizes[1] / 2;    // 800000
    const int* srcv = ei;
    const int* dstv = ei + E;

    char* w = (char*)d_ws;
    int*   cnt    = (int*)w;            w += (size_t)n * 4;
    int*   cursor = (int*)w;            w += (size_t)n * 4;
    int*   gcnt   = (int*)w;            w += 64 * 4;
    float* gsum   = (float*)w;          w += 64 * 64 * 4;
    size_t zbytes = (size_t)w - (size_t)d_ws;
    int*   csr_off= (int*)w;            w += (size_t)(n + 1) * 4;
    float* dinv   = (float*)w;          w += (size_t)n * 4;
    int*   csr_src= (int*)w;            w += (size_t)E * 4;
    int*   bsum   = (int*)w;            w += 256 * 4;
    int*   boff   = (int*)w;            w += 256 * 4;
    w = (char*)(((size_t)w + 255) & ~(size_t)255);
    float* hs = (float*)w;              w += (size_t)n * 64 * 4;
    float* hb = (float*)w;              w += (size_t)n * 64 * 4;

    hipMemsetAsync(d_ws, 0, zbytes, stream);

    int gE = (E + TPB - 1) / TPB;
    k_deg<<<gE, TPB, 0, stream>>>(dstv, E, cnt);

    int nb = (n + SCAN_CHUNK - 1) / SCAN_CHUNK;   // 49 for n=50000
    k_scan1<<<nb, TPB, 0, stream>>>(cnt, n, bsum);
    k_scan2<<<1, TPB, 0, stream>>>(bsum, nb, boff, csr_off, n);
    k_scan3<<<nb, TPB, 0, stream>>>(cnt, n, boff, csr_off, dinv);

    k_fill<<<gE, TPB, 0, stream>>>(srcv, dstv, E, csr_off, cursor, csr_src);

    int gRows = (n + 63) / 64;
    int gNode = (n + 3) / 4;
    k_gemm_scaled<256><<<gRows, TPB, 0, stream>>>(x, W1, dinv, hs, n);
    k_agg<<<gNode, TPB, 0, stream>>>(hs, csr_off, csr_src, dinv, b1, hb, n);
    k_gemm_scaled<64><<<gRows, TPB, 0, stream>>>(hb, W2, dinv, hs, n);
    k_agg<<<gNode, TPB, 0, stream>>>(hs, csr_off, csr_src, dinv, b2, hb, n);

    int nwaves16 = (n + 15) / 16;
    k_pool<<<(nwaves16 + 3) / 4, TPB, 0, stream>>>(hb, batch, n, gsum, gcnt);
    k_mlp<<<1, TPB, 0, stream>>>(gsum, gcnt, fc1w, fc1b, fc2w, fc2b, (float*)d_out);
}